// Round 4
// baseline (7123.611 us; speedup 1.0000x reference)
//
#include <hip/hip_runtime.h>

// ---------------------------------------------------------------------------
// Persistent fused 2-layer LSTM + FC for MI355X — v4: K-split waves.
//  - 128 WGs x 512 threads (8 waves), 4 batch-groups x 32 WGs.
//  - Per WG: 16 hidden units per layer. Wave roles:
//      w0: L0 units[0:8)  K[0:288)   w6: L0 units[0:8)  K[288:576)
//      w1: L0 units[8:16) K[0:288)   w7: L0 units[8:16) K[288:576)
//      w2: L1 units[0:8)  K[0:512)=Wih1*h0   w3: L1 units[0:8)  K[512:1024)=Whh1*h1
//      w4: L1 units[8:16) h0-half            w5: L1 units[8:16) h1-half
//    Helper waves (3,5,6,7) write f32x4 partials to LDS; final waves
//    (0,1,2,4) combine + gates + tagged h store.
//  - h exchange: u32 = fp16 | (tag<<16), 3-slot ring, agent-scope atomics,
//    speculative bulk read + per-word retry (v2 scheme, fewer consumers).
//  - Halves LLC traffic (8 MB/step) + producers/group (32) vs v2/v3.
// ---------------------------------------------------------------------------

#define H      512
#define T_SEQ  1024
#define DIN    64
#define STEPS  1025

#define SLOT_U32 16384          // [2 layers][16 batch][512 units] tagged u32
#define GRP_U32  49152          // 3 slots
#define WS_BYTES (4 * GRP_U32 * 4)

typedef _Float16 f16x8 __attribute__((ext_vector_type(8)));
typedef float    f32x4 __attribute__((ext_vector_type(4)));

__device__ __forceinline__ unsigned long long ld_u64(const unsigned long long* p) {
  return __hip_atomic_load((unsigned long long*)p, __ATOMIC_RELAXED, __HIP_MEMORY_SCOPE_AGENT);
}
__device__ __forceinline__ void st_u32(unsigned* p, unsigned v) {
  __hip_atomic_store(p, v, __ATOMIC_RELAXED, __HIP_MEMORY_SCOPE_AGENT);
}
__device__ __forceinline__ f16x8 pk8(float4 a, float4 b) {
  f16x8 r;
  r[0] = (_Float16)a.x; r[1] = (_Float16)a.y; r[2] = (_Float16)a.z; r[3] = (_Float16)a.w;
  r[4] = (_Float16)b.x; r[5] = (_Float16)b.y; r[6] = (_Float16)b.z; r[7] = (_Float16)b.w;
  return r;
}
__device__ __forceinline__ f16x8 cvt8(const float* p) {
  return pk8(*(const float4*)p, *(const float4*)(p + 4));
}
__device__ __forceinline__ f32x4 mfma16(f16x8 a, f16x8 b, f32x4 c) {
  return __builtin_amdgcn_mfma_f32_16x16x32_f16(a, b, c, 0, 0, 0);
}
__device__ __forceinline__ float rcpf_(float x) {
#if __has_builtin(__builtin_amdgcn_rcpf)
  return __builtin_amdgcn_rcpf(x);
#else
  return 1.0f / x;
#endif
}
__device__ __forceinline__ float sigm(float x) {
  x = fminf(fmaxf(x, -30.f), 30.f);
  return rcpf_(1.f + __expf(-x));
}
__device__ __forceinline__ float tanhx(float x) {
  x = fminf(fmaxf(x, -15.f), 15.f);
  float e = __expf(2.f * x);
  return (e - 1.f) * rcpf_(e + 1.f);
}

__global__ __launch_bounds__(512, 2)
void lstm_fused(const float* __restrict__ x,
                const float* __restrict__ Wih0, const float* __restrict__ Whh0,
                const float* __restrict__ bih0, const float* __restrict__ bhh0,
                const float* __restrict__ Wih1, const float* __restrict__ Whh1,
                const float* __restrict__ bih1, const float* __restrict__ bhh1,
                const float* __restrict__ fcw,  const float* __restrict__ fcb,
                float* __restrict__ out, unsigned* __restrict__ ws)
{
  // sH: [2 layers][16 batch][260 u32] staged h payload; pb: partial-sum buf
  __shared__ unsigned sH[2 * 16 * 260 + 2048];
  float* pb = (float*)(sH + 8320);

  const int tid  = threadIdx.x;
  const int wid  = blockIdx.x;
  const int g    = wid >> 5;           // batch group 0..3
  const int w    = wid & 31;           // WG within group
  const int wv   = tid >> 6;           // wave 0..7
  const int lane = tid & 63;
  const int bcol = lane & 15;          // batch-in-group (MFMA N col)
  const int kgrp = lane >> 4;
  const int U0   = w * 16;             // unit base of this WG (per layer)

  const int layer    = (wv >= 2 && wv <= 5) ? 1 : 0;
  const int hb       = U0 + ((wv == 1 || wv == 7 || wv == 4 || wv == 5) ? 8 : 0);
  const bool is_final  = (wv == 0 || wv == 1 || wv == 2 || wv == 4);
  const bool is_helper = !is_final;

  unsigned* gbase = ws + g * GRP_U32;

  // ---- resident weight A-fragments: 2 M-tiles (units hb..hb+3, hb+4..hb+7)
  //      M rows = gate-interleaved: row m -> gate m&3, unit_off m>>2
  const int src_m = lane & 15;
  const int gr0 = (src_m & 3) * H + hb + (src_m >> 2);
  const int gr1 = gr0 + 4;
  f16x8 wA[2][16];
  if (wv <= 1) {                       // L0 frags 0..8 (x: 0,1; h0: 2..8)
    #pragma unroll
    for (int f = 0; f < 9; ++f) {
      const float *p0, *p1;
      if (f < 2) {
        p0 = Wih0 + (size_t)gr0 * DIN + f * 32 + kgrp * 8;
        p1 = Wih0 + (size_t)gr1 * DIN + f * 32 + kgrp * 8;
      } else {
        p0 = Whh0 + (size_t)gr0 * H + (f - 2) * 32 + kgrp * 8;
        p1 = Whh0 + (size_t)gr1 * H + (f - 2) * 32 + kgrp * 8;
      }
      wA[0][f] = cvt8(p0); wA[1][f] = cvt8(p1);
    }
  } else if (wv >= 6) {                // L0 frags 9..17 (h0: K 224..512)
    #pragma unroll
    for (int q = 0; q < 9; ++q) {
      int col = (q + 7) * 32 + kgrp * 8;
      wA[0][q] = cvt8(Whh0 + (size_t)gr0 * H + col);
      wA[1][q] = cvt8(Whh0 + (size_t)gr1 * H + col);
    }
  } else if (wv == 2 || wv == 4) {     // L1 h0-half: Wih1 cols 0..511
    #pragma unroll
    for (int f = 0; f < 16; ++f) {
      int col = f * 32 + kgrp * 8;
      wA[0][f] = cvt8(Wih1 + (size_t)gr0 * H + col);
      wA[1][f] = cvt8(Wih1 + (size_t)gr1 * H + col);
    }
  } else {                             // wv 3,5: L1 h1-half: Whh1
    #pragma unroll
    for (int q = 0; q < 16; ++q) {
      int col = q * 32 + kgrp * 8;
      wA[0][q] = cvt8(Whh1 + (size_t)gr0 * H + col);
      wA[1][q] = cvt8(Whh1 + (size_t)gr1 * H + col);
    }
  }

  float bias[2][4];
  if (is_final) {
    const float* bi = layer ? bih1 : bih0;
    const float* bh = layer ? bhh1 : bhh0;
    #pragma unroll
    for (int t = 0; t < 2; ++t)
      #pragma unroll
      for (int r = 0; r < 4; ++r) {
        int u = hb + t * 4 + kgrp;
        bias[t][r] = bi[r * H + u] + bh[r * H + u];
      }
  }

  // zero LDS once: step 0 reads zeros as h_{-1}
  for (int i = tid; i < 2 * 16 * 260; i += 512) sH[i] = 0;
  __syncthreads();

  float cst0 = 0.f, cst1 = 0.f;
  unsigned spins = 0;
  const int rowb = bcol * 1040 + kgrp * 16;   // byte offset of B-frag row in sH

  for (int s = 0; s < STEPS; ++s) {
    // x prefetch for L0 low-K waves (frags 0,1)
    float4 xr0 = {0,0,0,0}, xr1 = xr0, xr2 = xr0, xr3 = xr0;
    if (wv <= 1) {
      int t = (s < T_SEQ) ? s : (T_SEQ - 1);
      const float* xp = x + ((size_t)((g * 16 + bcol) * T_SEQ + t)) * DIN + kgrp * 8;
      xr0 = *(const float4*)xp;        xr1 = *(const float4*)(xp + 4);
      xr2 = *(const float4*)(xp + 32); xr3 = *(const float4*)(xp + 36);
    }
    // speculative bulk read of tag-(s) data from slot (s-1)%3, per-word retry
    if (s > 0) {
      const unsigned long long* src =
          (const unsigned long long*)(gbase + ((s - 1) % 3) * SLOT_U32);
      const unsigned want = (unsigned)s;
      unsigned long long v[16];
      #pragma unroll
      for (int i = 0; i < 16; ++i) v[i] = ld_u64(src + tid + i * 512);
      for (;;) {
        unsigned bad = 0;
        #pragma unroll
        for (int i = 0; i < 16; ++i) {
          unsigned lo = (unsigned)v[i], hi = (unsigned)(v[i] >> 32);
          if (((lo >> 16) ^ want) | ((hi >> 16) ^ want)) bad |= (1u << i);
        }
        if (!bad) break;
        if (++spins > 2000000u) break;           // bounded anti-hang guard
        __builtin_amdgcn_s_sleep(1);
        #pragma unroll
        for (int i = 0; i < 16; ++i)
          if (bad & (1u << i)) v[i] = ld_u64(src + tid + i * 512);
      }
      #pragma unroll
      for (int i = 0; i < 16; ++i) {
        int j = tid + i * 512;                   // [2][16][256] u64 index
        unsigned payload = ((unsigned)v[i] & 0xffffu) | ((unsigned)(v[i] >> 32) << 16);
        sH[(j >> 12) * 4160 + ((j >> 8) & 15) * 260 + (j & 255)] = payload;
      }
    }
    __syncthreads();                             // B1: staged

    const bool act = layer ? (s > 0) : (s < T_SEQ);
    f32x4 acc0 = {0,0,0,0}, acc1 = {0,0,0,0};
    if (act) {
      const char* base0 = (const char*)sH;           // h0 region
      const char* base1 = (const char*)sH + 16640;   // h1 region
      if (wv <= 1) {
        f16x8 b0 = pk8(xr0, xr1);
        acc0 = mfma16(wA[0][0], b0, acc0); acc1 = mfma16(wA[1][0], b0, acc1);
        f16x8 b1 = pk8(xr2, xr3);
        acc0 = mfma16(wA[0][1], b1, acc0); acc1 = mfma16(wA[1][1], b1, acc1);
        #pragma unroll
        for (int f = 2; f < 9; ++f) {
          f16x8 bf = *(const f16x8*)(base0 + rowb + (f - 2) * 64);
          acc0 = mfma16(wA[0][f], bf, acc0); acc1 = mfma16(wA[1][f], bf, acc1);
        }
      } else if (wv >= 6) {
        #pragma unroll
        for (int q = 0; q < 9; ++q) {
          f16x8 bf = *(const f16x8*)(base0 + rowb + (q + 7) * 64);
          acc0 = mfma16(wA[0][q], bf, acc0); acc1 = mfma16(wA[1][q], bf, acc1);
        }
      } else if (wv == 2 || wv == 4) {
        #pragma unroll
        for (int f = 0; f < 16; ++f) {
          f16x8 bf = *(const f16x8*)(base0 + rowb + f * 64);
          acc0 = mfma16(wA[0][f], bf, acc0); acc1 = mfma16(wA[1][f], bf, acc1);
        }
      } else {
        #pragma unroll
        for (int q = 0; q < 16; ++q) {
          f16x8 bf = *(const f16x8*)(base1 + rowb + q * 64);
          acc0 = mfma16(wA[0][q], bf, acc0); acc1 = mfma16(wA[1][q], bf, acc1);
        }
      }
    }
    if (is_helper && act) {
      const int pidx = (wv == 6) ? 0 : (wv == 7) ? 1 : (wv == 3) ? 2 : 3;
      *(f32x4*)&pb[(pidx * 2 + 0) * 256 + lane * 4] = acc0;
      *(f32x4*)&pb[(pidx * 2 + 1) * 256 + lane * 4] = acc1;
    }
    __syncthreads();                             // B2: partials ready
    if (is_final) {
      float hv0 = 0.f, hv1 = 0.f;
      if (act) {
        const int pidx = (wv == 0) ? 0 : (wv == 1) ? 1 : (wv == 2) ? 2 : 3;
        acc0 += *(const f32x4*)&pb[(pidx * 2 + 0) * 256 + lane * 4];
        acc1 += *(const f32x4*)&pb[(pidx * 2 + 1) * 256 + lane * 4];
        {
          float ii = sigm(acc0[0] + bias[0][0]);
          float ff = sigm(acc0[1] + bias[0][1]);
          float gg = tanhx(acc0[2] + bias[0][2]);
          float oo = sigm(acc0[3] + bias[0][3]);
          cst0 = ff * cst0 + ii * gg;
          hv0 = oo * tanhx(cst0);
        }
        {
          float ii = sigm(acc1[0] + bias[1][0]);
          float ff = sigm(acc1[1] + bias[1][1]);
          float gg = tanhx(acc1[2] + bias[1][2]);
          float oo = sigm(acc1[3] + bias[1][3]);
          cst1 = ff * cst1 + ii * gg;
          hv1 = oo * tanhx(cst1);
        }
      }
      const bool produce = layer ? true : (s < T_SEQ);
      if (produce) {
        unsigned tag = (unsigned)(s + 1) << 16;
        unsigned u0 = (unsigned)__builtin_bit_cast(unsigned short, (_Float16)hv0);
        unsigned u1 = (unsigned)__builtin_bit_cast(unsigned short, (_Float16)hv1);
        unsigned* dst = gbase + (s % 3) * SLOT_U32 + layer * 8192
                      + bcol * 512 + hb + kgrp;
        st_u32(dst,     u0 | tag);
        st_u32(dst + 4, u1 | tag);               // unit +4 (tile 1)
      }
    }
  }

  // ---- FC epilogue: out = relu([h0_T; h1_T] @ fc_w^T + fc_b), [128][1024]
  __syncthreads();
  {
    const int rt = wid >> 4, ct = wid & 15;      // 8 row-tiles x 16 col-tiles
    const int sg = rt & 3;
    const bool isH1 = (rt >= 4);
    // h0_T: step 1023 -> slot 0, tag 1024; h1_T: step 1024 -> slot 1, tag 1025
    const unsigned want = isH1 ? (unsigned)STEPS : (unsigned)(STEPS - 1);
    const int     slot  = isH1 ? 1 : 0;
    const unsigned long long* src =
        (const unsigned long long*)(ws + sg * GRP_U32 + slot * SLOT_U32
                                    + (isH1 ? 8192 : 0));
    unsigned long long v[8];
    #pragma unroll
    for (int i = 0; i < 8; ++i) v[i] = ld_u64(src + tid + i * 512);
    for (;;) {
      unsigned bad = 0;
      #pragma unroll
      for (int i = 0; i < 8; ++i) {
        unsigned lo = (unsigned)v[i], hi = (unsigned)(v[i] >> 32);
        if (((lo >> 16) ^ want) | ((hi >> 16) ^ want)) bad |= (1u << i);
      }
      if (!bad) break;
      if (++spins > 2000000u) break;
      __builtin_amdgcn_s_sleep(1);
      #pragma unroll
      for (int i = 0; i < 8; ++i)
        if (bad & (1u << i)) v[i] = ld_u64(src + tid + i * 512);
    }
    #pragma unroll
    for (int i = 0; i < 8; ++i) {
      int j = tid + i * 512;                     // [16 batch][256 pairs]
      unsigned payload = ((unsigned)v[i] & 0xffffu) | ((unsigned)(v[i] >> 32) << 16);
      sH[(j >> 8) * 260 + (j & 255)] = payload;
    }
    __syncthreads();
    if (wv < 4) {
      const int col = ct * 64 + wv * 16 + bcol;
      f32x4 a0 = {0,0,0,0}, a1 = {0,0,0,0};
      #pragma unroll
      for (int f = 0; f < 16; ++f) {             // K = 512
        f16x8 af = *(const f16x8*)((const char*)sH + rowb + f * 64);
        f16x8 bf = cvt8(fcw + (size_t)col * H + f * 32 + kgrp * 8);
        if (f & 1) a1 = mfma16(af, bf, a1); else a0 = mfma16(af, bf, a0);
      }
      f32x4 a = a0 + a1;
      const float fb = fcb[col];
      #pragma unroll
      for (int r = 0; r < 4; ++r) {
        int row = rt * 16 + kgrp * 4 + r;
        float v2 = a[r] + fb;
        out[(size_t)row * 1024 + col] = v2 > 0.f ? v2 : 0.f;
      }
    }
  }
}

extern "C" void kernel_launch(void* const* d_in, const int* in_sizes, int n_in,
                              void* d_out, int out_size, void* d_ws, size_t ws_size,
                              hipStream_t stream) {
  const float* x    = (const float*)d_in[0];
  const float* Wih0 = (const float*)d_in[1];
  const float* Whh0 = (const float*)d_in[2];
  const float* bih0 = (const float*)d_in[3];
  const float* bhh0 = (const float*)d_in[4];
  const float* Wih1 = (const float*)d_in[5];
  const float* Whh1 = (const float*)d_in[6];
  const float* bih1 = (const float*)d_in[7];
  const float* bhh1 = (const float*)d_in[8];
  const float* fcw  = (const float*)d_in[9];
  const float* fcb  = (const float*)d_in[10];
  (void)in_sizes; (void)n_in; (void)out_size; (void)ws_size;

  // zero tag space every call (tag 0 never matches any wanted tag >= 1)
  hipMemsetAsync(d_ws, 0, WS_BYTES, stream);
  lstm_fused<<<dim3(128), dim3(512), 0, stream>>>(
      x, Wih0, Whh0, bih0, bhh0, Wih1, Whh1, bih1, bhh1, fcw, fcb,
      (float*)d_out, (unsigned*)d_ws);
}

// Round 6
// 4220.586 us; speedup vs baseline: 1.6878x; 1.6878x over previous
//
#include <hip/hip_runtime.h>

// ---------------------------------------------------------------------------
// Persistent fused 2-layer LSTM + FC for MI355X — v6: fat waves, half traffic.
//  - 128 WGs x 256 threads (4 waves), 4 batch-groups x 32 WGs.
//  - Every wave = full-K producer for 8 units of one layer:
//      wv0: L0 units [U0,U0+8)   wv1: L0 units [U0+8,U0+16)
//      wv2: L1 units [U0,U0+8)   wv3: L1 units [U0+8,U0+16)
//    (U0 = (wid&31)*16; K=576 for L0, K=1024 for L1; wA <= 256 VGPRs,
//     launch_bounds(256,1) => 512-VGPR budget, no v4-style spill.)
//  - h exchange: u32 = fp16|(tag<<16), 3-slot agent-scope ring (v2-proven),
//    speculative bulk read + per-word retry, double-buffered LDS staging
//    => ONE barrier per step.
//  - vs v2: producers/group 64->32, pollers 1024->512 waves, LLC traffic
//    16->8 MB/step. Tests the congestion/tail theory cleanly.
// ---------------------------------------------------------------------------

#define H      512
#define T_SEQ  1024
#define DIN    64
#define STEPS  1025

#define SLOT_U32 16384           // [2 layers][16 batch][512 units] tagged u32
#define GRP_U32  49152           // 3 slots
#define WS_BYTES (4 * GRP_U32 * 4)

typedef _Float16 f16x8 __attribute__((ext_vector_type(8)));
typedef float    f32x4 __attribute__((ext_vector_type(4)));

__device__ __forceinline__ unsigned long long ld_u64(const unsigned long long* p) {
  return __hip_atomic_load((unsigned long long*)p, __ATOMIC_RELAXED, __HIP_MEMORY_SCOPE_AGENT);
}
__device__ __forceinline__ void st_u32(unsigned* p, unsigned v) {
  __hip_atomic_store(p, v, __ATOMIC_RELAXED, __HIP_MEMORY_SCOPE_AGENT);
}
__device__ __forceinline__ f16x8 pk8(float4 a, float4 b) {
  f16x8 r;
  r[0] = (_Float16)a.x; r[1] = (_Float16)a.y; r[2] = (_Float16)a.z; r[3] = (_Float16)a.w;
  r[4] = (_Float16)b.x; r[5] = (_Float16)b.y; r[6] = (_Float16)b.z; r[7] = (_Float16)b.w;
  return r;
}
__device__ __forceinline__ f16x8 cvt8(const float* p) {
  return pk8(*(const float4*)p, *(const float4*)(p + 4));
}
__device__ __forceinline__ f32x4 mfma16(f16x8 a, f16x8 b, f32x4 c) {
  return __builtin_amdgcn_mfma_f32_16x16x32_f16(a, b, c, 0, 0, 0);
}
__device__ __forceinline__ float rcpf_(float x) {
#if __has_builtin(__builtin_amdgcn_rcpf)
  return __builtin_amdgcn_rcpf(x);
#else
  return 1.0f / x;
#endif
}
__device__ __forceinline__ float sigm(float x) {
  x = fminf(fmaxf(x, -30.f), 30.f);
  return rcpf_(1.f + __expf(-x));
}
__device__ __forceinline__ float tanhx(float x) {
  x = fminf(fmaxf(x, -15.f), 15.f);
  float e = __expf(2.f * x);
  return (e - 1.f) * rcpf_(e + 1.f);
}

__global__ __launch_bounds__(256, 1)
void lstm_fused(const float* __restrict__ x,
                const float* __restrict__ Wih0, const float* __restrict__ Whh0,
                const float* __restrict__ bih0, const float* __restrict__ bhh0,
                const float* __restrict__ Wih1, const float* __restrict__ Whh1,
                const float* __restrict__ bih1, const float* __restrict__ bhh1,
                const float* __restrict__ fcw,  const float* __restrict__ fcb,
                float* __restrict__ out, unsigned* __restrict__ ws)
{
  // double-buffered staged h: [buf][2 layers][16 batch][260 u32]
  __shared__ unsigned sH[2][8320];

  const int tid  = threadIdx.x;
  const int wid  = blockIdx.x;
  const int g    = wid >> 5;           // batch group 0..3
  const int w    = wid & 31;           // WG within group
  const int wv   = tid >> 6;           // wave 0..3
  const int lane = tid & 63;
  const int bcol = lane & 15;          // MFMA N col = batch-in-group
  const int kgrp = lane >> 4;
  const int layer = wv >> 1;
  const int hb    = w * 16 + (wv & 1) * 8;   // 8 units of this wave

  unsigned* gbase = ws + g * GRP_U32;

  // ---- resident weights: 2 M-tiles (units hb..+3, hb+4..+7), full K.
  //      M rows gate-interleaved: row m -> gate m&3, unit hb + (m>>2).
  const int src_m = lane & 15;
  const int gr0 = (src_m & 3) * H + hb + (src_m >> 2);   // PyTorch gate row
  const int gr1 = gr0 + 4;
  f16x8 wA[2][32];
  if (layer == 0) {                    // K = 64(x) + 512(h0): frags 0..17
    #pragma unroll
    for (int f = 0; f < 18; ++f) {
      const float *p0, *p1;
      if (f < 2) {
        p0 = Wih0 + (size_t)gr0 * DIN + f * 32 + kgrp * 8;
        p1 = Wih0 + (size_t)gr1 * DIN + f * 32 + kgrp * 8;
      } else {
        p0 = Whh0 + (size_t)gr0 * H + (f - 2) * 32 + kgrp * 8;
        p1 = Whh0 + (size_t)gr1 * H + (f - 2) * 32 + kgrp * 8;
      }
      wA[0][f] = cvt8(p0); wA[1][f] = cvt8(p1);
    }
  } else {                             // K = 512(h0) + 512(h1): frags 0..31
    #pragma unroll
    for (int f = 0; f < 16; ++f) {
      int col = f * 32 + kgrp * 8;
      wA[0][f] = cvt8(Wih1 + (size_t)gr0 * H + col);
      wA[1][f] = cvt8(Wih1 + (size_t)gr1 * H + col);
    }
    #pragma unroll
    for (int f = 16; f < 32; ++f) {
      int col = (f - 16) * 32 + kgrp * 8;
      wA[0][f] = cvt8(Whh1 + (size_t)gr0 * H + col);
      wA[1][f] = cvt8(Whh1 + (size_t)gr1 * H + col);
    }
  }
  float bias[2][4];
  {
    const float* bi = layer ? bih1 : bih0;
    const float* bh = layer ? bhh1 : bhh0;
    #pragma unroll
    for (int t = 0; t < 2; ++t)
      #pragma unroll
      for (int r = 0; r < 4; ++r) {
        int u = hb + t * 4 + kgrp;
        bias[t][r] = bi[r * H + u] + bh[r * H + u];
      }
  }

  // zero both staging buffers once (step 0 reads zeros as h_{-1})
  for (int i = tid; i < 2 * 8320; i += 256) ((unsigned*)sH)[i] = 0;
  __syncthreads();

  float cst0 = 0.f, cst1 = 0.f;
  unsigned spins = 0;                  // cumulative guard (normal use ~1e5)
  const int rowb = bcol * 1040 + kgrp * 16;   // byte offset of B-frag row

  for (int s = 0; s < STEPS; ++s) {
    // x prefetch for L0 waves (frags 0,1)
    float4 xr0 = {0,0,0,0}, xr1 = xr0, xr2 = xr0, xr3 = xr0;
    if (layer == 0) {
      int t = (s < T_SEQ) ? s : (T_SEQ - 1);
      const float* xp = x + ((size_t)((g * 16 + bcol) * T_SEQ + t)) * DIN + kgrp * 8;
      xr0 = *(const float4*)xp;        xr1 = *(const float4*)(xp + 4);
      xr2 = *(const float4*)(xp + 32); xr3 = *(const float4*)(xp + 36);
    }
    // stage tag-s data from slot (s-1)%3 into buf s&1 (2 passes x 16 u64)
    if (s > 0) {
      const unsigned long long* src =
          (const unsigned long long*)(gbase + ((s - 1) % 3) * SLOT_U32);
      const unsigned want = (unsigned)s;
      unsigned* dstbuf = sH[s & 1];
      #pragma unroll
      for (int pass = 0; pass < 2; ++pass) {
        unsigned long long v[16];
        #pragma unroll
        for (int i = 0; i < 16; ++i)
          v[i] = ld_u64(src + tid + (pass * 16 + i) * 256);
        for (;;) {
          unsigned bad = 0;
          #pragma unroll
          for (int i = 0; i < 16; ++i) {
            unsigned lo = (unsigned)v[i], hi = (unsigned)(v[i] >> 32);
            if (((lo >> 16) ^ want) | ((hi >> 16) ^ want)) bad |= (1u << i);
          }
          if (!bad) break;
          if (++spins > 8000000u) break;       // bounded anti-hang guard
          #pragma unroll
          for (int i = 0; i < 16; ++i)
            if (bad & (1u << i))
              v[i] = ld_u64(src + tid + (pass * 16 + i) * 256);
        }
        #pragma unroll
        for (int i = 0; i < 16; ++i) {
          int j = tid + (pass * 16 + i) * 256;   // [2][16][256] u64 index
          unsigned payload = ((unsigned)v[i] & 0xffffu)
                           | ((unsigned)(v[i] >> 32) << 16);
          dstbuf[(j >> 12) * 4160 + ((j >> 8) & 15) * 260 + (j & 255)] = payload;
        }
      }
    }
    __syncthreads();                             // staged; WAR handled by dbuf

    const bool act = layer ? (s > 0) : (s < T_SEQ);
    float hv0 = 0.f, hv1 = 0.f;
    if (act) {
      f32x4 acc0 = {0,0,0,0}, acc1 = {0,0,0,0};
      const char* cur = (const char*)sH[s & 1];
      if (layer == 0) {
        f16x8 b0 = pk8(xr0, xr1);
        acc0 = mfma16(wA[0][0], b0, acc0); acc1 = mfma16(wA[1][0], b0, acc1);
        f16x8 b1 = pk8(xr2, xr3);
        acc0 = mfma16(wA[0][1], b1, acc0); acc1 = mfma16(wA[1][1], b1, acc1);
        #pragma unroll
        for (int f = 2; f < 18; ++f) {
          f16x8 bf = *(const f16x8*)(cur + rowb + (f - 2) * 64);
          acc0 = mfma16(wA[0][f], bf, acc0); acc1 = mfma16(wA[1][f], bf, acc1);
        }
      } else {
        #pragma unroll
        for (int f = 0; f < 16; ++f) {
          f16x8 bf = *(const f16x8*)(cur + rowb + f * 64);
          acc0 = mfma16(wA[0][f], bf, acc0); acc1 = mfma16(wA[1][f], bf, acc1);
        }
        #pragma unroll
        for (int f = 16; f < 32; ++f) {
          f16x8 bf = *(const f16x8*)(cur + 16640 + rowb + (f - 16) * 64);
          acc0 = mfma16(wA[0][f], bf, acc0); acc1 = mfma16(wA[1][f], bf, acc1);
        }
      }
      {
        float ii = sigm(acc0[0] + bias[0][0]);
        float ff = sigm(acc0[1] + bias[0][1]);
        float gg = tanhx(acc0[2] + bias[0][2]);
        float oo = sigm(acc0[3] + bias[0][3]);
        cst0 = ff * cst0 + ii * gg;
        hv0 = oo * tanhx(cst0);
      }
      {
        float ii = sigm(acc1[0] + bias[1][0]);
        float ff = sigm(acc1[1] + bias[1][1]);
        float gg = tanhx(acc1[2] + bias[1][2]);
        float oo = sigm(acc1[3] + bias[1][3]);
        cst1 = ff * cst1 + ii * gg;
        hv1 = oo * tanhx(cst1);
      }
    }
    const bool produce = layer ? true : (s < T_SEQ);   // L1 emits zeros at s=0
    if (produce) {
      unsigned tag = (unsigned)(s + 1) << 16;
      unsigned u0 = (unsigned)__builtin_bit_cast(unsigned short, (_Float16)hv0);
      unsigned u1 = (unsigned)__builtin_bit_cast(unsigned short, (_Float16)hv1);
      unsigned* dst = gbase + (s % 3) * SLOT_U32 + layer * 8192
                    + bcol * 512 + hb + kgrp;
      st_u32(dst,     u0 | tag);                 // unit hb+kgrp
      st_u32(dst + 4, u1 | tag);                 // unit hb+kgrp+4
    }
    // no trailing barrier: next step writes the OTHER LDS buffer
  }

  __syncthreads();                               // main-loop reads done

  // ---- FC epilogue: out = relu([h0_T; h1_T] @ fc_w^T + fc_b), [128][1024]
  {
    const int rt = wid >> 4, ct = wid & 15;      // 8 row-tiles x 16 col-tiles
    const int sg = rt & 3;
    const bool isH1 = (rt >= 4);
    // h0_T: step 1023 -> slot 0, tag 1024; h1_T: step 1024 -> slot 1, tag 1025
    const unsigned want = isH1 ? (unsigned)STEPS : (unsigned)(STEPS - 1);
    const int     slot  = isH1 ? 1 : 0;
    const unsigned long long* src =
        (const unsigned long long*)(ws + sg * GRP_U32 + slot * SLOT_U32
                                    + (isH1 ? 8192 : 0));
    unsigned long long v[16];
    #pragma unroll
    for (int i = 0; i < 16; ++i) v[i] = ld_u64(src + tid + i * 256);
    for (;;) {
      unsigned bad = 0;
      #pragma unroll
      for (int i = 0; i < 16; ++i) {
        unsigned lo = (unsigned)v[i], hi = (unsigned)(v[i] >> 32);
        if (((lo >> 16) ^ want) | ((hi >> 16) ^ want)) bad |= (1u << i);
      }
      if (!bad) break;
      if (++spins > 8000000u) break;
      #pragma unroll
      for (int i = 0; i < 16; ++i)
        if (bad & (1u << i)) v[i] = ld_u64(src + tid + i * 256);
    }
    #pragma unroll
    for (int i = 0; i < 16; ++i) {
      int j = tid + i * 256;                     // [16 batch][256 pairs]
      unsigned payload = ((unsigned)v[i] & 0xffffu)
                       | ((unsigned)(v[i] >> 32) << 16);
      sH[0][(j >> 8) * 260 + (j & 255)] = payload;
    }
    __syncthreads();
    const int col = ct * 64 + wv * 16 + bcol;
    f32x4 a0 = {0,0,0,0}, a1 = {0,0,0,0};
    #pragma unroll
    for (int f = 0; f < 16; ++f) {               // K = 512
      f16x8 af = *(const f16x8*)((const char*)sH[0] + rowb + f * 64);
      f16x8 bf = cvt8(fcw + (size_t)col * H + f * 32 + kgrp * 8);
      if (f & 1) a1 = mfma16(af, bf, a1); else a0 = mfma16(af, bf, a0);
    }
    f32x4 a = a0 + a1;
    const float fb = fcb[col];
    #pragma unroll
    for (int r = 0; r < 4; ++r) {
      int row = rt * 16 + kgrp * 4 + r;
      float v2 = a[r] + fb;
      out[(size_t)row * 1024 + col] = v2 > 0.f ? v2 : 0.f;
    }
  }
}

extern "C" void kernel_launch(void* const* d_in, const int* in_sizes, int n_in,
                              void* d_out, int out_size, void* d_ws, size_t ws_size,
                              hipStream_t stream) {
  const float* x    = (const float*)d_in[0];
  const float* Wih0 = (const float*)d_in[1];
  const float* Whh0 = (const float*)d_in[2];
  const float* bih0 = (const float*)d_in[3];
  const float* bhh0 = (const float*)d_in[4];
  const float* Wih1 = (const float*)d_in[5];
  const float* Whh1 = (const float*)d_in[6];
  const float* bih1 = (const float*)d_in[7];
  const float* bhh1 = (const float*)d_in[8];
  const float* fcw  = (const float*)d_in[9];
  const float* fcb  = (const float*)d_in[10];
  (void)in_sizes; (void)n_in; (void)out_size; (void)ws_size;

  // zero tag space every call (tag 0 never matches any wanted tag >= 1)
  hipMemsetAsync(d_ws, 0, WS_BYTES, stream);
  lstm_fused<<<dim3(128), dim3(256), 0, stream>>>(
      x, Wih0, Whh0, bih0, bhh0, Wih1, Whh1, bih1, bhh1, fcw, fcb,
      (float*)d_out, (unsigned*)d_ws);
}